// Round 3
// baseline (663.382 us; speedup 1.0000x reference)
//
#include <hip/hip_runtime.h>
#include <hip/hip_bf16.h>

// QuantizedLinear: out[M,N] = (x[M,K] @ W^T) * scale + bias, W[N,K] = q - zp
// M = 8192, N = 4096, K = 4096.
// R2: (a) cvt_x fused into GEMM — A staged as fp32 via global_load_lds,
//     converted to bf16 at fragment-read (VALU has slack: 44% busy).
//     (b) XOR chunk-swizzle on staging source addresses kills the 8-way
//     LDS bank conflicts (3.35e7 conflict cycles = ~13% of GEMM wall).
//     W still pre-converted to bf16 (exact: |q-zp| < 256).

typedef __bf16 bf16x8 __attribute__((ext_vector_type(8)));
typedef float  f32x4  __attribute__((ext_vector_type(4)));

#define BM 128
#define BN 128
#define BK 32

// ---------------- W conversion (int32 -> bf16, exact) ----------------

__global__ __launch_bounds__(256) void cvt_w_bf16(
    const int4* __restrict__ q, const int* __restrict__ zp,
    uint2* __restrict__ o, int n4) {
  int t = blockIdx.x * 256 + threadIdx.x;
  int T = gridDim.x * 256;
  int z = zp[0];
  for (int i = t; i < n4; i += T) {
    int4 a = q[i];
    union { __bf16 h[4]; uint2 u; } ra;
    ra.h[0] = (__bf16)(float)(a.x - z); ra.h[1] = (__bf16)(float)(a.y - z);
    ra.h[2] = (__bf16)(float)(a.z - z); ra.h[3] = (__bf16)(float)(a.w - z);
    o[i] = ra.u;
  }
}

// ---------------- fused GEMM ----------------
// A[M,K] fp32 row-major (raw x), Bw[N,K] bf16 row-major.
// LDS A-tile: fp32 [128][32], rows = 128 B = 8 chunks of 16 B.
//   Staged swizzled: LDS[row][c] = glob[row][c ^ (row&7)].
// LDS B-tile: bf16 [128][32], rows = 64 B = 4 chunks of 16 B.
//   Staged swizzled: LDS[row][c] = glob[row][c ^ ((row>>1)&3)].

__global__ __launch_bounds__(256) void gemm_fused(
    const float* __restrict__ A, const __bf16* __restrict__ Bw,
    const float* __restrict__ scale, const float* __restrict__ bias,
    float* __restrict__ C, int M, int N, int K) {
  __shared__ float  As[BM * BK];   // 16 KB
  __shared__ __bf16 Bs[BN * BK];   // 8 KB

  const int tid  = threadIdx.x;
  const int wave = tid >> 6;
  const int lane = tid & 63;

  const int m0 = blockIdx.y * BM;
  const int n0 = blockIdx.x * BN;

  // ---- staging lane maps ----
  // A (fp32): 8 chunk-lanes x 8 rows per instr; 4 instrs cover 32 rows/wave.
  const int a_r8 = lane >> 3;                 // 0..7
  const int a_c  = lane & 7;                  // chunk 0..7
  const int a_g  = a_c ^ (a_r8 & 7);          // swizzled source chunk
  // B (bf16): 4 chunk-lanes x 16 rows per instr; 2 instrs cover 32 rows/wave.
  const int b_r16 = lane >> 2;                // 0..15
  const int b_c   = lane & 3;                 // chunk 0..3
  const int b_g   = b_c ^ ((b_r16 >> 1) & 3); // swizzled source chunk

  const float*  Ag = A  + (size_t)(m0 + wave * 32 + a_r8) * K + a_g * 4;
  const __bf16* Bg = Bw + (size_t)(n0 + wave * 32 + b_r16) * K + b_g * 8;
  float*  Asl = As + (wave * 32) * BK;        // wave-uniform LDS bases
  __bf16* Bsl = Bs + (wave * 32) * BK;

  // ---- compute maps: 2x2 waves of 64x64, 4x4 frags of 16x16 ----
  const int wm   = (wave >> 1) * 64;
  const int wn   = (wave & 1) * 64;
  const int fr   = lane & 15;
  const int quad = lane >> 4;

  f32x4 acc[4][4] = {};

  for (int k0 = 0; k0 < K; k0 += BK) {
    // A: 4 instrs, 8 rows each (rows 0,8,16,24 within the wave's 32)
#pragma unroll
    for (int r = 0; r < 4; r++)
      __builtin_amdgcn_global_load_lds(
          (const __attribute__((address_space(1))) void*)(Ag + (size_t)(r * 8) * K + k0),
          (__attribute__((address_space(3))) void*)(Asl + r * 8 * BK), 16, 0, 0);
    // B: 2 instrs, 16 rows each
#pragma unroll
    for (int r = 0; r < 2; r++)
      __builtin_amdgcn_global_load_lds(
          (const __attribute__((address_space(1))) void*)(Bg + (size_t)(r * 16) * K + k0),
          (__attribute__((address_space(3))) void*)(Bsl + r * 16 * BK), 16, 0, 0);
    __syncthreads();

    bf16x8 af[4], bfr[4];
#pragma unroll
    for (int i = 0; i < 4; i++) {
      const int ar = wm + i * 16 + fr;
      const float* pa = As + ar * BK;
      f32x4 lo = *(const f32x4*)(pa + (((2 * quad)     ^ (ar & 7)) * 4));
      f32x4 hi = *(const f32x4*)(pa + (((2 * quad + 1) ^ (ar & 7)) * 4));
#pragma unroll
      for (int e = 0; e < 4; e++) {
        af[i][e]     = (__bf16)lo[e];
        af[i][e + 4] = (__bf16)hi[e];
      }
    }
#pragma unroll
    for (int j = 0; j < 4; j++) {
      const int br = wn + j * 16 + fr;
      bfr[j] = *(const bf16x8*)(Bs + br * BK + ((quad ^ ((br >> 1) & 3)) * 8));
    }

#pragma unroll
    for (int i = 0; i < 4; i++)
#pragma unroll
      for (int j = 0; j < 4; j++)
        acc[i][j] = __builtin_amdgcn_mfma_f32_16x16x32_bf16(
            af[i], bfr[j], acc[i][j], 0, 0, 0);
    __syncthreads();
  }

  // epilogue: C/D layout col = lane&15, row = quad*4 + reg (m89-verified)
  const float s = scale[0];
#pragma unroll
  for (int i = 0; i < 4; i++) {
    const int row = m0 + wm + i * 16 + quad * 4;
#pragma unroll
    for (int j = 0; j < 4; j++) {
      const int col = n0 + wn + j * 16 + fr;
      const float bv = bias[col];
      float* cp = C + (size_t)row * N + col;
#pragma unroll
      for (int r = 0; r < 4; r++)
        cp[(size_t)r * N] = s * acc[i][j][r] + bv;
    }
  }
}

// ---------------- launch ----------------

extern "C" void kernel_launch(void* const* d_in, const int* in_sizes, int n_in,
                              void* d_out, int out_size, void* d_ws, size_t ws_size,
                              hipStream_t stream) {
  const int M = 8192, N = 4096, K = 4096;

  const float* x    = (const float*)d_in[0];
  const int*   qw   = (const int*)d_in[1];
  const int*   zp   = (const int*)d_in[2];
  const float* sc   = (const float*)d_in[3];
  const float* bias = (const float*)d_in[4];
  float* out = (float*)d_out;

  __bf16* w_bf = (__bf16*)d_ws;

  {
    int n4 = (N * K) / 4;  // 4,194,304 int4s
    cvt_w_bf16<<<2048, 256, 0, stream>>>((const int4*)qw, zp, (uint2*)w_bf, n4);
  }

  dim3 grid(N / BN, M / BM);  // (32, 64)
  gemm_fused<<<grid, 256, 0, stream>>>(x, w_bf, sc, bias, out, M, N, K);
}